// Round 1
// baseline (389.887 us; speedup 1.0000x reference)
//
#include <hip/hip_runtime.h>
#include <math.h>

#define I_N 128
#define C_N 128
#define R_N 36
#define W_N 24
#define D_N 512

// ---------------------------------------------------------------------------
// Kernel 1: per-image Gram matrices G[i][r1][r2] = dot(images[i,r1], images[i,r2])
// grid: 128 blocks, 256 threads. Thread grid 12x12, 3x3 micro-tile.
// ---------------------------------------------------------------------------
__global__ __launch_bounds__(256) void gram_kernel(const float* __restrict__ images,
                                                   float* __restrict__ G) {
    __shared__ float tile[R_N][68];  // 36 x 64 chunk, stride 68 keeps float4 align + banks spread
    const int i = blockIdx.x;
    const float* img = images + (size_t)i * R_N * D_N;
    const int tid = threadIdx.x;
    const int t1 = (tid / 12) * 3;
    const int t2 = (tid % 12) * 3;
    const bool active = tid < 144;
    float acc[3][3] = {{0.f,0.f,0.f},{0.f,0.f,0.f},{0.f,0.f,0.f}};
    for (int k0 = 0; k0 < D_N; k0 += 64) {
        // stage 36x64 floats as float4 (576 float4s)
        for (int idx = tid; idx < R_N * 16; idx += 256) {
            int r = idx / 16, k4 = idx % 16;
            float4 v = *(const float4*)(img + (size_t)r * D_N + k0 + k4 * 4);
            *(float4*)&tile[r][k4 * 4] = v;
        }
        __syncthreads();
        if (active) {
            #pragma unroll
            for (int k = 0; k < 64; k += 4) {
                float4 a0 = *(const float4*)&tile[t1 + 0][k];
                float4 a1 = *(const float4*)&tile[t1 + 1][k];
                float4 a2 = *(const float4*)&tile[t1 + 2][k];
                float4 b0 = *(const float4*)&tile[t2 + 0][k];
                float4 b1 = *(const float4*)&tile[t2 + 1][k];
                float4 b2 = *(const float4*)&tile[t2 + 2][k];
                acc[0][0] += a0.x*b0.x + a0.y*b0.y + a0.z*b0.z + a0.w*b0.w;
                acc[0][1] += a0.x*b1.x + a0.y*b1.y + a0.z*b1.z + a0.w*b1.w;
                acc[0][2] += a0.x*b2.x + a0.y*b2.y + a0.z*b2.z + a0.w*b2.w;
                acc[1][0] += a1.x*b0.x + a1.y*b0.y + a1.z*b0.z + a1.w*b0.w;
                acc[1][1] += a1.x*b1.x + a1.y*b1.y + a1.z*b1.z + a1.w*b1.w;
                acc[1][2] += a1.x*b2.x + a1.y*b2.y + a1.z*b2.z + a1.w*b2.w;
                acc[2][0] += a2.x*b0.x + a2.y*b0.y + a2.z*b0.z + a2.w*b0.w;
                acc[2][1] += a2.x*b1.x + a2.y*b1.y + a2.z*b1.z + a2.w*b1.w;
                acc[2][2] += a2.x*b2.x + a2.y*b2.y + a2.z*b2.z + a2.w*b2.w;
            }
        }
        __syncthreads();
    }
    if (active) {
        float* gp = G + (size_t)i * R_N * R_N;
        #pragma unroll
        for (int a = 0; a < 3; ++a)
            #pragma unroll
            for (int b = 0; b < 3; ++b)
                gp[(t1 + a) * R_N + (t2 + b)] = acc[a][b];
    }
}

// ---------------------------------------------------------------------------
// Kernel 2: caption L2 norms per (c,w). grid 3072 blocks x 64 threads.
// ---------------------------------------------------------------------------
__global__ __launch_bounds__(64) void capnorm_kernel(const float* __restrict__ caps,
                                                     float* __restrict__ capn) {
    const int row = blockIdx.x;  // c*24 + w
    const float* p = caps + (size_t)row * D_N;
    float s = 0.f;
    for (int k = threadIdx.x * 2; k < D_N; k += 128) {
        float2 v = *(const float2*)(p + k);
        s += v.x * v.x + v.y * v.y;
    }
    #pragma unroll
    for (int off = 32; off > 0; off >>= 1) s += __shfl_down(s, off);
    if (threadIdx.x == 0) capn[row] = sqrtf(s);
}

// ---------------------------------------------------------------------------
// Kernel 3: attn GEMM (fp32 vector). A = images flat (4608 x 512),
// B = captions slab rows. Output attn[c_local][i][r][w].
// BM=64, BN=96 (=4 captions), BK=32, 256 threads, 4x6 micro-tile.
// ---------------------------------------------------------------------------
#define BM 64
#define BN 96
#define BK 32

__global__ __launch_bounds__(256) void attn_gemm_kernel(const float* __restrict__ images,
                                                        const float* __restrict__ captions,
                                                        float* __restrict__ attn, int c0) {
    __shared__ float As[BK][BM];  // transposed: As[k][m]
    __shared__ float Bs[BK][BN];
    const int m0 = blockIdx.x * BM;
    const int nbase = blockIdx.y * BN;  // local col within slab
    const float* Brow = captions + (size_t)c0 * W_N * D_N;
    const int tid = threadIdx.x;
    const int tx = tid % 16, ty = tid / 16;
    const int kc = (tid % 8) * 4;
    const int rr = tid / 8;

    float acc[4][6];
    #pragma unroll
    for (int a = 0; a < 4; ++a)
        #pragma unroll
        for (int b = 0; b < 6; ++b) acc[a][b] = 0.f;

    for (int k0 = 0; k0 < D_N; k0 += BK) {
        // stage A 64x32 (transposed into LDS)
        {
            float4 v0 = *(const float4*)(images + (size_t)(m0 + rr) * D_N + k0 + kc);
            float4 v1 = *(const float4*)(images + (size_t)(m0 + rr + 32) * D_N + k0 + kc);
            As[kc + 0][rr] = v0.x; As[kc + 1][rr] = v0.y; As[kc + 2][rr] = v0.z; As[kc + 3][rr] = v0.w;
            As[kc + 0][rr + 32] = v1.x; As[kc + 1][rr + 32] = v1.y; As[kc + 2][rr + 32] = v1.z; As[kc + 3][rr + 32] = v1.w;
        }
        // stage B 96x32
        #pragma unroll
        for (int bb = 0; bb < BN; bb += 32) {
            float4 v = *(const float4*)(Brow + (size_t)(nbase + rr + bb) * D_N + k0 + kc);
            Bs[kc + 0][rr + bb] = v.x; Bs[kc + 1][rr + bb] = v.y;
            Bs[kc + 2][rr + bb] = v.z; Bs[kc + 3][rr + bb] = v.w;
        }
        __syncthreads();
        #pragma unroll
        for (int kk = 0; kk < BK; ++kk) {
            float4 av = *(const float4*)&As[kk][ty * 4];
            float2 b01 = *(const float2*)&Bs[kk][tx * 6 + 0];
            float2 b23 = *(const float2*)&Bs[kk][tx * 6 + 2];
            float2 b45 = *(const float2*)&Bs[kk][tx * 6 + 4];
            float a[4] = {av.x, av.y, av.z, av.w};
            float b[6] = {b01.x, b01.y, b23.x, b23.y, b45.x, b45.y};
            #pragma unroll
            for (int mm = 0; mm < 4; ++mm)
                #pragma unroll
                for (int nn = 0; nn < 6; ++nn) acc[mm][nn] += a[mm] * b[nn];
        }
        __syncthreads();
    }
    // store to attn[cl][i][r][w]
    #pragma unroll
    for (int mm = 0; mm < 4; ++mm) {
        int row = m0 + ty * 4 + mm;
        int i = row / R_N, r = row % R_N;
        #pragma unroll
        for (int nn = 0; nn < 6; ++nn) {
            int ncol = nbase + tx * 6 + nn;
            int cl = ncol / W_N, w = ncol % W_N;
            attn[(((size_t)cl * I_N + i) * R_N + r) * W_N + w] = acc[mm][nn];
        }
    }
}

// ---------------------------------------------------------------------------
// Kernel 4: per-(c,i) score. grid (cs_n, 128), 64 threads (1 wave).
// Computes leaky+mask+w-norm, softmax over r, num = sum_r s*raw,
// ||wei||^2 = s^T G s (Gram trick), cos, masked LSE over w -> row_sim.
// ---------------------------------------------------------------------------
__global__ __launch_bounds__(64) void score_kernel(const float* __restrict__ attn,
                                                   const float* __restrict__ G,
                                                   const float* __restrict__ capn,
                                                   const int* __restrict__ cap_lens,
                                                   float* __restrict__ scores, int c0) {
    __shared__ float sm_l[R_N][25];    // logits, later exp values (padded)
    __shared__ float sm_raw[R_N][25];  // raw attn (padded)
    __shared__ float gsh[R_N * R_N];
    __shared__ float red[W_N];
    const int cl = blockIdx.x, i = blockIdx.y;
    const int c = c0 + cl;
    const int lane = threadIdx.x;
    const int len = cap_lens[c];

    const float* gp = G + (size_t)i * R_N * R_N;
    for (int idx = lane; idx < R_N * R_N; idx += 64) gsh[idx] = gp[idx];

    const float* at = attn + ((size_t)cl * I_N + i) * R_N * W_N;
    if (lane < R_N) {
        float raw[W_N];
        #pragma unroll
        for (int w4 = 0; w4 < W_N; w4 += 4) {
            float4 v = *(const float4*)(at + lane * W_N + w4);
            raw[w4] = v.x; raw[w4 + 1] = v.y; raw[w4 + 2] = v.z; raw[w4 + 3] = v.w;
        }
        float ss = 0.f;
        float aa[W_N];
        #pragma unroll
        for (int w = 0; w < W_N; ++w) {
            float x = raw[w];
            x = x > 0.f ? x : 0.1f * x;
            x = (w < len) ? x : 0.f;
            aa[w] = x;
            ss += x * x;
        }
        float scl = 9.0f / (sqrtf(ss) + 1e-8f);
        #pragma unroll
        for (int w = 0; w < W_N; ++w) {
            sm_l[lane][w] = aa[w] * scl;
            sm_raw[lane][w] = raw[w];
        }
    }
    __syncthreads();
    // phase 2a: softmax stats per w (lanes 0..23)
    float Z = 0.f, num_u = 0.f;
    if (lane < W_N) {
        const int w = lane;
        float mx = -3.4e38f;
        #pragma unroll
        for (int r = 0; r < R_N; ++r) mx = fmaxf(mx, sm_l[r][w]);
        #pragma unroll
        for (int r = 0; r < R_N; ++r) {
            float e = expf(sm_l[r][w] - mx);
            Z += e;
            num_u += e * sm_raw[r][w];
            sm_l[r][w] = e;  // overwrite own column with exp values
        }
    }
    __syncthreads();
    // phase 2b: wn_u = e^T G e, split over 48 lanes (w, half of r2 range)
    float wn = 0.f;
    if (lane < 48) {
        const int w = lane % W_N;
        const bool hi = lane >= W_N;  // r2 in [18,36) for hi half
        float scol[R_N];
        #pragma unroll
        for (int r = 0; r < R_N; ++r) scol[r] = sm_l[r][w];
        #pragma unroll
        for (int r2 = 0; r2 < 18; ++r2) {
            int r2g = hi ? (r2 + 18) : r2;
            const float4* g4 = (const float4*)&gsh[r2g * R_N];
            float t = 0.f;
            #pragma unroll
            for (int q = 0; q < 9; ++q) {
                float4 g = g4[q];
                t += g.x * scol[4 * q] + g.y * scol[4 * q + 1] + g.z * scol[4 * q + 2] + g.w * scol[4 * q + 3];
            }
            float sv = hi ? scol[r2 + 18] : scol[r2];  // static indices + select
            wn += t * sv;
        }
    }
    wn += __shfl_down(wn, 24);
    if (lane < W_N) {
        const int w = lane;
        float invZ = 1.f / Z;
        float num = num_u * invZ;
        float wnorm = sqrtf(fmaxf(wn, 0.f)) * invZ;
        float den = fmaxf(capn[c * W_N + w] * wnorm, 1e-8f);
        float cosv = num / den;
        red[w] = (w < len) ? cosv * 6.0f : -3.4e38f;
    }
    __syncthreads();
    if (lane == 0) {
        float mx = -3.4e38f;
        #pragma unroll
        for (int w = 0; w < W_N; ++w) mx = fmaxf(mx, red[w]);
        float se = 0.f;
        #pragma unroll
        for (int w = 0; w < W_N; ++w) se += expf(red[w] - mx);
        scores[(size_t)c * I_N + i] = (mx + logf(se)) / 6.0f;
    }
}

// ---------------------------------------------------------------------------
// Kernel 5: final hinge loss. 1 block x 128 threads.
// scores layout: scores[c*128 + i] = row_sim[c][i]; scores_mat[i][c] = ws[c*128+i].
// ---------------------------------------------------------------------------
__global__ __launch_bounds__(128) void final_kernel(const float* __restrict__ scores,
                                                    float* __restrict__ out) {
    __shared__ float diag[C_N];
    __shared__ float red[C_N];
    const int t = threadIdx.x;
    diag[t] = scores[t * C_N + t];
    __syncthreads();
    const float di = diag[t];
    float cs = 0.f, cim = 0.f;
    for (int k = 0; k < C_N; ++k) {
        if (k == t) continue;
        float vs = 0.2f + scores[k * C_N + t] - di;  // cost_s[i=t, c=k]
        float vi = 0.2f + scores[t * C_N + k] - di;  // cost_im[i=k, c=t]
        cs = fmaxf(cs, vs);
        cim = fmaxf(cim, vi);
    }
    red[t] = cs + cim;
    __syncthreads();
    #pragma unroll
    for (int off = 64; off > 0; off >>= 1) {
        if (t < off) red[t] += red[t + off];
        __syncthreads();
    }
    if (t == 0) out[0] = red[0];
}

// ---------------------------------------------------------------------------
extern "C" void kernel_launch(void* const* d_in, const int* in_sizes, int n_in,
                              void* d_out, int out_size, void* d_ws, size_t ws_size,
                              hipStream_t stream) {
    (void)in_sizes; (void)n_in; (void)out_size;
    const float* images = (const float*)d_in[0];
    const float* captions = (const float*)d_in[1];
    const int* cap_lens = (const int*)d_in[2];
    float* out = (float*)d_out;
    float* ws = (float*)d_ws;

    // workspace layout (floats)
    const size_t G_OFF = 0;
    const size_t G_SZ = (size_t)I_N * R_N * R_N;       // 165888
    const size_t CN_OFF = G_OFF + G_SZ;
    const size_t CN_SZ = (size_t)C_N * W_N;            // 3072
    const size_t SC_OFF = CN_OFF + CN_SZ;
    const size_t SC_SZ = (size_t)C_N * I_N;            // 16384
    const size_t AT_OFF = SC_OFF + SC_SZ;

    float* Gw = ws + G_OFF;
    float* capn = ws + CN_OFF;
    float* scores = ws + SC_OFF;
    float* attn = ws + AT_OFF;

    const size_t per_c = (size_t)I_N * R_N * W_N;  // 110592 floats per caption slab unit
    size_t fixed_bytes = AT_OFF * sizeof(float);
    size_t avail_floats = (ws_size > fixed_bytes) ? (ws_size - fixed_bytes) / sizeof(float) : 0;
    int cslab = (int)(avail_floats / per_c);
    if (cslab > C_N) cslab = C_N;
    cslab &= ~3;           // multiple of 4 (BN=96 = 4 captions)
    if (cslab < 4) cslab = 4;

    gram_kernel<<<I_N, 256, 0, stream>>>(images, Gw);
    capnorm_kernel<<<C_N * W_N, 64, 0, stream>>>(captions, capn);

    for (int c0 = 0; c0 < C_N; c0 += cslab) {
        int cs_n = C_N - c0;
        if (cs_n > cslab) cs_n = cslab;
        dim3 g1((I_N * R_N) / BM, (cs_n * W_N) / BN);
        attn_gemm_kernel<<<g1, 256, 0, stream>>>(images, captions, attn, c0);
        dim3 g2(cs_n, I_N);
        score_kernel<<<g2, 64, 0, stream>>>(attn, Gw, capn, cap_lens, scores, c0);
    }
    final_kernel<<<1, 128, 0, stream>>>(scores, out);
}

// Round 2
// 192.196 us; speedup vs baseline: 2.0286x; 2.0286x over previous
//
#include <hip/hip_runtime.h>
#include <math.h>

#define I_N 128
#define C_N 128
#define R_N 36
#define W_N 24
#define D_N 512
#define M_N (I_N * R_N)   // 4608
#define N_N (C_N * W_N)   // 3072

typedef __attribute__((ext_vector_type(8))) short bf16x8;
typedef __attribute__((ext_vector_type(4))) float f32x4;
typedef __attribute__((ext_vector_type(8))) unsigned short u16x8;

__device__ inline float bf2f(unsigned short u) {
    return __uint_as_float(((unsigned int)u) << 16);
}
__device__ inline unsigned short f2bf(float f) {
    unsigned int u = __float_as_uint(f);
    u = (u + 0x7FFFu + ((u >> 16) & 1u)) >> 16;
    return (unsigned short)u;
}
__device__ inline void gload_lds16(const void* g, void* l) {
    __builtin_amdgcn_global_load_lds(
        (const __attribute__((address_space(1))) void*)g,
        (__attribute__((address_space(3))) void*)l, 16, 0, 0);
}

// ---------------------------------------------------------------------------
// Kernel 0: fp32 -> bf16 conversion of images and captions.
// 8 floats per thread. 1920 blocks x 256 threads covers both arrays exactly.
// ---------------------------------------------------------------------------
__global__ __launch_bounds__(256) void convert_kernel(const float* __restrict__ images,
                                                      const float* __restrict__ captions,
                                                      unsigned short* __restrict__ imgbf,
                                                      unsigned short* __restrict__ capbf) {
    const int NI = M_N * D_N / 8;   // 294912
    const int NC = N_N * D_N / 8;   // 196608
    int idx = blockIdx.x * 256 + threadIdx.x;
    const float* src;
    unsigned short* dst;
    int g;
    if (idx < NI) { src = images; dst = imgbf; g = idx; }
    else if (idx < NI + NC) { src = captions; dst = capbf; g = idx - NI; }
    else return;
    float4 v0 = *(const float4*)(src + (size_t)g * 8);
    float4 v1 = *(const float4*)(src + (size_t)g * 8 + 4);
    u16x8 o;
    o[0] = f2bf(v0.x); o[1] = f2bf(v0.y); o[2] = f2bf(v0.z); o[3] = f2bf(v0.w);
    o[4] = f2bf(v1.x); o[5] = f2bf(v1.y); o[6] = f2bf(v1.z); o[7] = f2bf(v1.w);
    *(u16x8*)(dst + (size_t)g * 8) = o;
}

// ---------------------------------------------------------------------------
// Kernel 1: per-image Gram matrices G[i][r1][r2] = dot(images[i,r1], images[i,r2])
// (fp32, exact). grid: 128 blocks, 256 threads.
// ---------------------------------------------------------------------------
__global__ __launch_bounds__(256) void gram_kernel(const float* __restrict__ images,
                                                   float* __restrict__ G) {
    __shared__ float tile[R_N][68];
    const int i = blockIdx.x;
    const float* img = images + (size_t)i * R_N * D_N;
    const int tid = threadIdx.x;
    const int t1 = (tid / 12) * 3;
    const int t2 = (tid % 12) * 3;
    const bool active = tid < 144;
    float acc[3][3] = {{0.f,0.f,0.f},{0.f,0.f,0.f},{0.f,0.f,0.f}};
    for (int k0 = 0; k0 < D_N; k0 += 64) {
        for (int idx = tid; idx < R_N * 16; idx += 256) {
            int r = idx / 16, k4 = idx % 16;
            float4 v = *(const float4*)(img + (size_t)r * D_N + k0 + k4 * 4);
            *(float4*)&tile[r][k4 * 4] = v;
        }
        __syncthreads();
        if (active) {
            #pragma unroll
            for (int k = 0; k < 64; k += 4) {
                float4 a0 = *(const float4*)&tile[t1 + 0][k];
                float4 a1 = *(const float4*)&tile[t1 + 1][k];
                float4 a2 = *(const float4*)&tile[t1 + 2][k];
                float4 b0 = *(const float4*)&tile[t2 + 0][k];
                float4 b1 = *(const float4*)&tile[t2 + 1][k];
                float4 b2 = *(const float4*)&tile[t2 + 2][k];
                acc[0][0] += a0.x*b0.x + a0.y*b0.y + a0.z*b0.z + a0.w*b0.w;
                acc[0][1] += a0.x*b1.x + a0.y*b1.y + a0.z*b1.z + a0.w*b1.w;
                acc[0][2] += a0.x*b2.x + a0.y*b2.y + a0.z*b2.z + a0.w*b2.w;
                acc[1][0] += a1.x*b0.x + a1.y*b0.y + a1.z*b0.z + a1.w*b0.w;
                acc[1][1] += a1.x*b1.x + a1.y*b1.y + a1.z*b1.z + a1.w*b1.w;
                acc[1][2] += a1.x*b2.x + a1.y*b2.y + a1.z*b2.z + a1.w*b2.w;
                acc[2][0] += a2.x*b0.x + a2.y*b0.y + a2.z*b0.z + a2.w*b0.w;
                acc[2][1] += a2.x*b1.x + a2.y*b1.y + a2.z*b1.z + a2.w*b1.w;
                acc[2][2] += a2.x*b2.x + a2.y*b2.y + a2.z*b2.z + a2.w*b2.w;
            }
        }
        __syncthreads();
    }
    if (active) {
        float* gp = G + (size_t)i * R_N * R_N;
        #pragma unroll
        for (int a = 0; a < 3; ++a)
            #pragma unroll
            for (int b = 0; b < 3; ++b)
                gp[(t1 + a) * R_N + (t2 + b)] = acc[a][b];
    }
}

// ---------------------------------------------------------------------------
// Kernel 2: caption L2 norms per (c,w). grid 3072 blocks x 64 threads.
// ---------------------------------------------------------------------------
__global__ __launch_bounds__(64) void capnorm_kernel(const float* __restrict__ caps,
                                                     float* __restrict__ capn) {
    const int row = blockIdx.x;
    const float* p = caps + (size_t)row * D_N;
    float s = 0.f;
    for (int k = threadIdx.x * 2; k < D_N; k += 128) {
        float2 v = *(const float2*)(p + k);
        s += v.x * v.x + v.y * v.y;
    }
    #pragma unroll
    for (int off = 32; off > 0; off >>= 1) s += __shfl_down(s, off);
    if (threadIdx.x == 0) capn[row] = sqrtf(s);
}

// ---------------------------------------------------------------------------
// Kernel 3: attn GEMM, bf16 MFMA. A = imagesbf (4608x512), B = capsbf (3072x512,
// row-major N x K = B^T form). C[row][col] -> attn bf16 [c][i][r][w].
// 128x128 tile, BK=32, 4 waves, each wave 64x64 via 4x4 frags of 16x16x32.
// ---------------------------------------------------------------------------
#define BM 128
#define BN 128
#define BK 32

__global__ __launch_bounds__(256) void attn_gemm_kernel(const unsigned short* __restrict__ A,
                                                        const unsigned short* __restrict__ B,
                                                        unsigned short* __restrict__ attn) {
    __shared__ unsigned short As[BM * BK];
    __shared__ unsigned short Bs[BN * BK];
    const int m0 = blockIdx.x * BM;
    const int n0 = blockIdx.y * BN;
    const int tid = threadIdx.x;
    const int lane = tid & 63;
    const int wid = tid >> 6;
    const int wr = wid >> 1, wc = wid & 1;
    const int fr = lane & 15;   // fragment M/N index
    const int fk = lane >> 4;   // k-group

    f32x4 acc[4][4];
    #pragma unroll
    for (int m = 0; m < 4; ++m)
        #pragma unroll
        for (int n = 0; n < 4; ++n) acc[m][n] = (f32x4){0.f, 0.f, 0.f, 0.f};

    for (int k0 = 0; k0 < D_N; k0 += BK) {
        // stage 128x32 bf16 tiles (16 KB total) via global_load_lds x16B
        #pragma unroll
        for (int it = 0; it < 4; ++it) {
            int nch = it * 256 + tid;            // 16B chunk id, 0..1023
            int row = nch >> 2, kc = (nch & 3) * 8;
            gload_lds16(A + (size_t)(m0 + row) * D_N + k0 + kc, (char*)As + nch * 16);
            gload_lds16(B + (size_t)(n0 + row) * D_N + k0 + kc, (char*)Bs + nch * 16);
        }
        __syncthreads();
        bf16x8 af[4], bfr[4];
        #pragma unroll
        for (int m = 0; m < 4; ++m)
            af[m] = *(const bf16x8*)&As[(wr * 64 + m * 16 + fr) * BK + fk * 8];
        #pragma unroll
        for (int n = 0; n < 4; ++n)
            bfr[n] = *(const bf16x8*)&Bs[(wc * 64 + n * 16 + fr) * BK + fk * 8];
        #pragma unroll
        for (int m = 0; m < 4; ++m)
            #pragma unroll
            for (int n = 0; n < 4; ++n)
                acc[m][n] = __builtin_amdgcn_mfma_f32_16x16x32_bf16(af[m], bfr[n], acc[m][n], 0, 0, 0);
        __syncthreads();
    }
    // epilogue: row = m0+wr*64+m*16+fk*4+j (i,r), col = n0+wc*64+n*16+fr (c,w)
    #pragma unroll
    for (int m = 0; m < 4; ++m) {
        #pragma unroll
        for (int n = 0; n < 4; ++n) {
            #pragma unroll
            for (int j = 0; j < 4; ++j) {
                int row = m0 + wr * 64 + m * 16 + fk * 4 + j;
                int col = n0 + wc * 64 + n * 16 + fr;
                int i = row / R_N, r = row - i * R_N;
                int c = col / W_N, w = col - c * W_N;
                attn[(((size_t)c * I_N + i) * R_N + r) * W_N + w] = f2bf(acc[m][n][j]);
            }
        }
    }
}

// ---------------------------------------------------------------------------
// Kernel 4: per-(c,i) score. grid (128, 128), 64 threads (1 wave).
// ---------------------------------------------------------------------------
__global__ __launch_bounds__(64) void score_kernel(const unsigned short* __restrict__ attn,
                                                   const float* __restrict__ G,
                                                   const float* __restrict__ capn,
                                                   const int* __restrict__ cap_lens,
                                                   float* __restrict__ scores) {
    __shared__ float sm_l[R_N][25];
    __shared__ float sm_raw[R_N][25];
    __shared__ float gsh[R_N * R_N];
    __shared__ float red[W_N];
    const int c = blockIdx.x, i = blockIdx.y;
    const int lane = threadIdx.x;
    const int len = cap_lens[c];

    const float* gp = G + (size_t)i * R_N * R_N;
    for (int idx = lane; idx < R_N * R_N; idx += 64) gsh[idx] = gp[idx];

    const unsigned short* at = attn + ((size_t)c * I_N + i) * R_N * W_N;
    if (lane < R_N) {
        u16x8 p0 = *(const u16x8*)(at + lane * W_N);
        u16x8 p1 = *(const u16x8*)(at + lane * W_N + 8);
        u16x8 p2 = *(const u16x8*)(at + lane * W_N + 16);
        float raw[W_N];
        #pragma unroll
        for (int q = 0; q < 8; ++q) {
            raw[q] = bf2f(p0[q]);
            raw[q + 8] = bf2f(p1[q]);
            raw[q + 16] = bf2f(p2[q]);
        }
        float ss = 0.f;
        float aa[W_N];
        #pragma unroll
        for (int w = 0; w < W_N; ++w) {
            float x = raw[w];
            x = x > 0.f ? x : 0.1f * x;
            x = (w < len) ? x : 0.f;
            aa[w] = x;
            ss += x * x;
        }
        float scl = 9.0f / (sqrtf(ss) + 1e-8f);
        #pragma unroll
        for (int w = 0; w < W_N; ++w) {
            sm_l[lane][w] = aa[w] * scl;
            sm_raw[lane][w] = raw[w];
        }
    }
    __syncthreads();
    float Z = 0.f, num_u = 0.f;
    if (lane < W_N) {
        const int w = lane;
        float mx = -3.4e38f;
        #pragma unroll
        for (int r = 0; r < R_N; ++r) mx = fmaxf(mx, sm_l[r][w]);
        #pragma unroll
        for (int r = 0; r < R_N; ++r) {
            float e = expf(sm_l[r][w] - mx);
            Z += e;
            num_u += e * sm_raw[r][w];
            sm_l[r][w] = e;
        }
    }
    __syncthreads();
    float wn = 0.f;
    if (lane < 48) {
        const int w = lane % W_N;
        const bool hi = lane >= W_N;
        float scol[R_N];
        #pragma unroll
        for (int r = 0; r < R_N; ++r) scol[r] = sm_l[r][w];
        #pragma unroll
        for (int r2 = 0; r2 < 18; ++r2) {
            int r2g = hi ? (r2 + 18) : r2;
            const float4* g4 = (const float4*)&gsh[r2g * R_N];
            float t = 0.f;
            #pragma unroll
            for (int q = 0; q < 9; ++q) {
                float4 g = g4[q];
                t += g.x * scol[4 * q] + g.y * scol[4 * q + 1] + g.z * scol[4 * q + 2] + g.w * scol[4 * q + 3];
            }
            float sv = hi ? scol[r2 + 18] : scol[r2];
            wn += t * sv;
        }
    }
    wn += __shfl_down(wn, 24);
    if (lane < W_N) {
        const int w = lane;
        float invZ = 1.f / Z;
        float num = num_u * invZ;
        float wnorm = sqrtf(fmaxf(wn, 0.f)) * invZ;
        float den = fmaxf(capn[c * W_N + w] * wnorm, 1e-8f);
        float cosv = num / den;
        red[w] = (w < len) ? cosv * 6.0f : -3.4e38f;
    }
    __syncthreads();
    if (lane == 0) {
        float mx = -3.4e38f;
        #pragma unroll
        for (int w = 0; w < W_N; ++w) mx = fmaxf(mx, red[w]);
        float se = 0.f;
        #pragma unroll
        for (int w = 0; w < W_N; ++w) se += expf(red[w] - mx);
        scores[(size_t)c * I_N + i] = (mx + logf(se)) / 6.0f;
    }
}

// ---------------------------------------------------------------------------
// Kernel 5: final hinge loss. 1 block x 128 threads.
// ---------------------------------------------------------------------------
__global__ __launch_bounds__(128) void final_kernel(const float* __restrict__ scores,
                                                    float* __restrict__ out) {
    __shared__ float diag[C_N];
    __shared__ float red[C_N];
    const int t = threadIdx.x;
    diag[t] = scores[t * C_N + t];
    __syncthreads();
    const float di = diag[t];
    float cs = 0.f, cim = 0.f;
    for (int k = 0; k < C_N; ++k) {
        if (k == t) continue;
        float vs = 0.2f + scores[k * C_N + t] - di;
        float vi = 0.2f + scores[t * C_N + k] - di;
        cs = fmaxf(cs, vs);
        cim = fmaxf(cim, vi);
    }
    red[t] = cs + cim;
    __syncthreads();
    #pragma unroll
    for (int off = 64; off > 0; off >>= 1) {
        if (t < off) red[t] += red[t + off];
        __syncthreads();
    }
    if (t == 0) out[0] = red[0];
}

// ---------------------------------------------------------------------------
extern "C" void kernel_launch(void* const* d_in, const int* in_sizes, int n_in,
                              void* d_out, int out_size, void* d_ws, size_t ws_size,
                              hipStream_t stream) {
    (void)in_sizes; (void)n_in; (void)out_size; (void)ws_size;
    const float* images = (const float*)d_in[0];
    const float* captions = (const float*)d_in[1];
    const int* cap_lens = (const int*)d_in[2];
    float* out = (float*)d_out;

    char* wsb = (char*)d_ws;
    size_t off = 0;
    auto alloc = [&](size_t bytes) -> char* {
        char* p = wsb + off;
        off += (bytes + 255) & ~(size_t)255;
        return p;
    };
    unsigned short* imgbf = (unsigned short*)alloc((size_t)M_N * D_N * 2);
    unsigned short* capbf = (unsigned short*)alloc((size_t)N_N * D_N * 2);
    float* Gw = (float*)alloc((size_t)I_N * R_N * R_N * 4);
    float* capn = (float*)alloc((size_t)C_N * W_N * 4);
    float* scores = (float*)alloc((size_t)C_N * I_N * 4);
    unsigned short* attn = (unsigned short*)alloc((size_t)C_N * I_N * R_N * W_N * 2);

    convert_kernel<<<1920, 256, 0, stream>>>(images, captions, imgbf, capbf);
    gram_kernel<<<I_N, 256, 0, stream>>>(images, Gw);
    capnorm_kernel<<<C_N * W_N, 64, 0, stream>>>(captions, capn);
    attn_gemm_kernel<<<dim3(M_N / BM, N_N / BN), 256, 0, stream>>>(imgbf, capbf, attn);
    score_kernel<<<dim3(C_N, I_N), 64, 0, stream>>>(attn, Gw, capn, cap_lens, scores);
    final_kernel<<<1, 128, 0, stream>>>(scores, out);
}

// Round 3
// 173.727 us; speedup vs baseline: 2.2442x; 1.1063x over previous
//
#include <hip/hip_runtime.h>
#include <math.h>

#define I_N 128
#define C_N 128
#define R_N 36
#define W_N 24
#define D_N 512
#define M_N (I_N * R_N)   // 4608
#define N_N (C_N * W_N)   // 3072

typedef __attribute__((ext_vector_type(8))) short bf16x8;
typedef __attribute__((ext_vector_type(4))) float f32x4;
typedef __attribute__((ext_vector_type(8))) unsigned short u16x8;

__device__ inline float bf2f(unsigned short u) {
    return __uint_as_float(((unsigned int)u) << 16);
}
__device__ inline unsigned short f2bf(float f) {
    unsigned int u = __float_as_uint(f);
    u = (u + 0x7FFFu + ((u >> 16) & 1u)) >> 16;
    return (unsigned short)u;
}
__device__ inline void gload_lds16(const void* g, void* l) {
    __builtin_amdgcn_global_load_lds(
        (const __attribute__((address_space(1))) void*)g,
        (__attribute__((address_space(3))) void*)l, 16, 0, 0);
}

// ---------------------------------------------------------------------------
// Kernel 0: fp32 -> bf16 conversion of images and captions.
// ---------------------------------------------------------------------------
__global__ __launch_bounds__(256) void convert_kernel(const float* __restrict__ images,
                                                      const float* __restrict__ captions,
                                                      unsigned short* __restrict__ imgbf,
                                                      unsigned short* __restrict__ capbf) {
    const int NI = M_N * D_N / 8;   // 294912
    const int NC = N_N * D_N / 8;   // 196608
    int idx = blockIdx.x * 256 + threadIdx.x;
    const float* src;
    unsigned short* dst;
    int g;
    if (idx < NI) { src = images; dst = imgbf; g = idx; }
    else if (idx < NI + NC) { src = captions; dst = capbf; g = idx - NI; }
    else return;
    float4 v0 = *(const float4*)(src + (size_t)g * 8);
    float4 v1 = *(const float4*)(src + (size_t)g * 8 + 4);
    u16x8 o;
    o[0] = f2bf(v0.x); o[1] = f2bf(v0.y); o[2] = f2bf(v0.z); o[3] = f2bf(v0.w);
    o[4] = f2bf(v1.x); o[5] = f2bf(v1.y); o[6] = f2bf(v1.z); o[7] = f2bf(v1.w);
    *(u16x8*)(dst + (size_t)g * 8) = o;
}

// ---------------------------------------------------------------------------
// Kernel 1: per-image Gram matrices G[i][r1][r2] (fp32, exact).
// ---------------------------------------------------------------------------
__global__ __launch_bounds__(256) void gram_kernel(const float* __restrict__ images,
                                                   float* __restrict__ G) {
    __shared__ float tile[R_N][68];
    const int i = blockIdx.x;
    const float* img = images + (size_t)i * R_N * D_N;
    const int tid = threadIdx.x;
    const int t1 = (tid / 12) * 3;
    const int t2 = (tid % 12) * 3;
    const bool active = tid < 144;
    float acc[3][3] = {{0.f,0.f,0.f},{0.f,0.f,0.f},{0.f,0.f,0.f}};
    for (int k0 = 0; k0 < D_N; k0 += 64) {
        for (int idx = tid; idx < R_N * 16; idx += 256) {
            int r = idx / 16, k4 = idx % 16;
            float4 v = *(const float4*)(img + (size_t)r * D_N + k0 + k4 * 4);
            *(float4*)&tile[r][k4 * 4] = v;
        }
        __syncthreads();
        if (active) {
            #pragma unroll
            for (int k = 0; k < 64; k += 4) {
                float4 a0 = *(const float4*)&tile[t1 + 0][k];
                float4 a1 = *(const float4*)&tile[t1 + 1][k];
                float4 a2 = *(const float4*)&tile[t1 + 2][k];
                float4 b0 = *(const float4*)&tile[t2 + 0][k];
                float4 b1 = *(const float4*)&tile[t2 + 1][k];
                float4 b2 = *(const float4*)&tile[t2 + 2][k];
                acc[0][0] += a0.x*b0.x + a0.y*b0.y + a0.z*b0.z + a0.w*b0.w;
                acc[0][1] += a0.x*b1.x + a0.y*b1.y + a0.z*b1.z + a0.w*b1.w;
                acc[0][2] += a0.x*b2.x + a0.y*b2.y + a0.z*b2.z + a0.w*b2.w;
                acc[1][0] += a1.x*b0.x + a1.y*b0.y + a1.z*b0.z + a1.w*b0.w;
                acc[1][1] += a1.x*b1.x + a1.y*b1.y + a1.z*b1.z + a1.w*b1.w;
                acc[1][2] += a1.x*b2.x + a1.y*b2.y + a1.z*b2.z + a1.w*b2.w;
                acc[2][0] += a2.x*b0.x + a2.y*b0.y + a2.z*b0.z + a2.w*b0.w;
                acc[2][1] += a2.x*b1.x + a2.y*b1.y + a2.z*b1.z + a2.w*b1.w;
                acc[2][2] += a2.x*b2.x + a2.y*b2.y + a2.z*b2.z + a2.w*b2.w;
            }
        }
        __syncthreads();
    }
    if (active) {
        float* gp = G + (size_t)i * R_N * R_N;
        #pragma unroll
        for (int a = 0; a < 3; ++a)
            #pragma unroll
            for (int b = 0; b < 3; ++b)
                gp[(t1 + a) * R_N + (t2 + b)] = acc[a][b];
    }
}

// ---------------------------------------------------------------------------
// Kernel 2: caption L2 norms per (c,w).
// ---------------------------------------------------------------------------
__global__ __launch_bounds__(64) void capnorm_kernel(const float* __restrict__ caps,
                                                     float* __restrict__ capn) {
    const int row = blockIdx.x;
    const float* p = caps + (size_t)row * D_N;
    float s = 0.f;
    for (int k = threadIdx.x * 2; k < D_N; k += 128) {
        float2 v = *(const float2*)(p + k);
        s += v.x * v.x + v.y * v.y;
    }
    #pragma unroll
    for (int off = 32; off > 0; off >>= 1) s += __shfl_down(s, off);
    if (threadIdx.x == 0) capn[row] = sqrtf(s);
}

// ---------------------------------------------------------------------------
// Kernel 3: attn GEMM, bf16 MFMA. Output attn bf16 [i][c][r][w].
// ---------------------------------------------------------------------------
#define BM 128
#define BN 128
#define BK 32

__global__ __launch_bounds__(256) void attn_gemm_kernel(const unsigned short* __restrict__ A,
                                                        const unsigned short* __restrict__ B,
                                                        unsigned short* __restrict__ attn) {
    __shared__ unsigned short As[BM * BK];
    __shared__ unsigned short Bs[BN * BK];
    const int m0 = blockIdx.x * BM;
    const int n0 = blockIdx.y * BN;
    const int tid = threadIdx.x;
    const int lane = tid & 63;
    const int wid = tid >> 6;
    const int wr = wid >> 1, wc = wid & 1;
    const int fr = lane & 15;
    const int fk = lane >> 4;

    f32x4 acc[4][4];
    #pragma unroll
    for (int m = 0; m < 4; ++m)
        #pragma unroll
        for (int n = 0; n < 4; ++n) acc[m][n] = (f32x4){0.f, 0.f, 0.f, 0.f};

    for (int k0 = 0; k0 < D_N; k0 += BK) {
        #pragma unroll
        for (int it = 0; it < 4; ++it) {
            int nch = it * 256 + tid;
            int row = nch >> 2, kc = (nch & 3) * 8;
            gload_lds16(A + (size_t)(m0 + row) * D_N + k0 + kc, (char*)As + nch * 16);
            gload_lds16(B + (size_t)(n0 + row) * D_N + k0 + kc, (char*)Bs + nch * 16);
        }
        __syncthreads();
        bf16x8 af[4], bfr[4];
        #pragma unroll
        for (int m = 0; m < 4; ++m)
            af[m] = *(const bf16x8*)&As[(wr * 64 + m * 16 + fr) * BK + fk * 8];
        #pragma unroll
        for (int n = 0; n < 4; ++n)
            bfr[n] = *(const bf16x8*)&Bs[(wc * 64 + n * 16 + fr) * BK + fk * 8];
        #pragma unroll
        for (int m = 0; m < 4; ++m)
            #pragma unroll
            for (int n = 0; n < 4; ++n)
                acc[m][n] = __builtin_amdgcn_mfma_f32_16x16x32_bf16(af[m], bfr[n], acc[m][n], 0, 0, 0);
        __syncthreads();
    }
    // epilogue: row -> (i,r), col -> (c,w); attn[i][c][r][w]
    #pragma unroll
    for (int m = 0; m < 4; ++m) {
        #pragma unroll
        for (int n = 0; n < 4; ++n) {
            #pragma unroll
            for (int j = 0; j < 4; ++j) {
                int row = m0 + wr * 64 + m * 16 + fk * 4 + j;
                int col = n0 + wc * 64 + n * 16 + fr;
                int i = row / R_N, r = row - i * R_N;
                int c = col / W_N, w = col - c * W_N;
                attn[(((size_t)i * C_N + c) * R_N + r) * W_N + w] = f2bf(acc[m][n][j]);
            }
        }
    }
}

// ---------------------------------------------------------------------------
// Kernel 4: score. grid (128 i, 16 c-groups), 192 threads.
// Phase A: per-row scale (288 rows). Phase B: one thread per (c,w) column
// (exactly 192): softmax over r (no max-sub; logits bounded by 9), num,
// e^T G e via uniform-broadcast float4 LDS reads, logit. Then per-c LSE.
// ---------------------------------------------------------------------------
#define CG 8

__global__ __launch_bounds__(192) void score_kernel(const unsigned short* __restrict__ attn,
                                                    const float* __restrict__ G,
                                                    const float* __restrict__ capn,
                                                    const int* __restrict__ cap_lens,
                                                    float* __restrict__ scores) {
    __shared__ unsigned short stage[CG * R_N * W_N];  // 13824 B
    __shared__ float gsh[R_N * R_N];                  // 5184 B
    __shared__ float scl_sh[CG][R_N];
    __shared__ float red[CG][W_N];
    __shared__ int len_sh[CG];
    const int i = blockIdx.x;
    const int c0 = blockIdx.y * CG;
    const int tid = threadIdx.x;

    const float* gp = G + (size_t)i * R_N * R_N;
    for (int idx = tid; idx < R_N * R_N; idx += 192) gsh[idx] = gp[idx];
    if (tid < CG) len_sh[tid] = cap_lens[c0 + tid];
    // stage 8 captions' attn rows, coalesced 16B chunks
    const unsigned short* at = attn + ((size_t)i * C_N + c0) * R_N * W_N;
    for (int ch = tid; ch < CG * R_N * W_N / 8; ch += 192)
        *(u16x8*)&stage[ch * 8] = *(const u16x8*)(at + ch * 8);
    __syncthreads();

    // Phase A: per-row masked-leaky norm -> scale
    for (int row = tid; row < CG * R_N; row += 192) {
        int cl = row / R_N, r = row - cl * R_N;
        int len = len_sh[cl];
        const unsigned short* rp = &stage[(cl * R_N + r) * W_N];
        u16x8 p0 = *(const u16x8*)&rp[0];
        u16x8 p1 = *(const u16x8*)&rp[8];
        u16x8 p2 = *(const u16x8*)&rp[16];
        float ss = 0.f;
        #pragma unroll
        for (int q = 0; q < 8; ++q) {
            float x0 = bf2f(p0[q]); x0 = x0 > 0.f ? x0 : 0.1f * x0; x0 = (q      < len) ? x0 : 0.f;
            float x1 = bf2f(p1[q]); x1 = x1 > 0.f ? x1 : 0.1f * x1; x1 = (q + 8  < len) ? x1 : 0.f;
            float x2 = bf2f(p2[q]); x2 = x2 > 0.f ? x2 : 0.1f * x2; x2 = (q + 16 < len) ? x2 : 0.f;
            ss += x0 * x0 + x1 * x1 + x2 * x2;
        }
        scl_sh[cl][r] = 9.0f / (sqrtf(ss) + 1e-8f);
    }
    __syncthreads();

    // Phase B: one thread per (c,w) column
    {
        const int cl = tid / W_N, w = tid - cl * W_N;
        const int len = len_sh[cl];
        const bool valid = w < len;
        float e[R_N];
        float Z = 0.f, num = 0.f;
        #pragma unroll
        for (int r = 0; r < R_N; ++r) {
            float raw = bf2f(stage[(cl * R_N + r) * W_N + w]);
            float x = raw > 0.f ? raw : 0.1f * raw;
            float l = valid ? x * scl_sh[cl][r] : 0.f;
            float ev = __expf(l);
            e[r] = ev;
            Z += ev;
            num += ev * raw;
        }
        float wn = 0.f;
        #pragma unroll
        for (int r2 = 0; r2 < R_N; ++r2) {
            const float4* g4 = (const float4*)&gsh[r2 * R_N];
            float t = 0.f;
            #pragma unroll
            for (int q = 0; q < 9; ++q) {
                float4 g = g4[q];
                t += g.x * e[4 * q] + g.y * e[4 * q + 1] + g.z * e[4 * q + 2] + g.w * e[4 * q + 3];
            }
            wn += t * e[r2];
        }
        float invZ = 1.f / Z;
        float den = fmaxf(capn[(c0 + cl) * W_N + w] * sqrtf(fmaxf(wn, 0.f)) * invZ, 1e-8f);
        float cosv = (num * invZ) / den;
        red[cl][w] = valid ? cosv * 6.0f : -3.4e38f;
    }
    __syncthreads();
    if (tid < CG) {
        float se = 0.f;
        #pragma unroll
        for (int w = 0; w < W_N; ++w) se += __expf(red[tid][w] - 6.0f);
        scores[(size_t)(c0 + tid) * I_N + i] = (__logf(se) + 6.0f) / 6.0f;
    }
}

// ---------------------------------------------------------------------------
// Kernel 5: final hinge loss. 1 block x 128 threads.
// ---------------------------------------------------------------------------
__global__ __launch_bounds__(128) void final_kernel(const float* __restrict__ scores,
                                                    float* __restrict__ out) {
    __shared__ float diag[C_N];
    __shared__ float red[C_N];
    const int t = threadIdx.x;
    diag[t] = scores[t * C_N + t];
    __syncthreads();
    const float di = diag[t];
    float cs = 0.f, cim = 0.f;
    for (int k = 0; k < C_N; ++k) {
        if (k == t) continue;
        float vs = 0.2f + scores[k * C_N + t] - di;
        float vi = 0.2f + scores[t * C_N + k] - di;
        cs = fmaxf(cs, vs);
        cim = fmaxf(cim, vi);
    }
    red[t] = cs + cim;
    __syncthreads();
    #pragma unroll
    for (int off = 64; off > 0; off >>= 1) {
        if (t < off) red[t] += red[t + off];
        __syncthreads();
    }
    if (t == 0) out[0] = red[0];
}

// ---------------------------------------------------------------------------
extern "C" void kernel_launch(void* const* d_in, const int* in_sizes, int n_in,
                              void* d_out, int out_size, void* d_ws, size_t ws_size,
                              hipStream_t stream) {
    (void)in_sizes; (void)n_in; (void)out_size; (void)ws_size;
    const float* images = (const float*)d_in[0];
    const float* captions = (const float*)d_in[1];
    const int* cap_lens = (const int*)d_in[2];
    float* out = (float*)d_out;

    char* wsb = (char*)d_ws;
    size_t off = 0;
    auto alloc = [&](size_t bytes) -> char* {
        char* p = wsb + off;
        off += (bytes + 255) & ~(size_t)255;
        return p;
    };
    unsigned short* imgbf = (unsigned short*)alloc((size_t)M_N * D_N * 2);
    unsigned short* capbf = (unsigned short*)alloc((size_t)N_N * D_N * 2);
    float* Gw = (float*)alloc((size_t)I_N * R_N * R_N * 4);
    float* capn = (float*)alloc((size_t)C_N * W_N * 4);
    float* scores = (float*)alloc((size_t)C_N * I_N * 4);
    unsigned short* attn = (unsigned short*)alloc((size_t)I_N * C_N * R_N * W_N * 2);

    convert_kernel<<<1920, 256, 0, stream>>>(images, captions, imgbf, capbf);
    gram_kernel<<<I_N, 256, 0, stream>>>(images, Gw);
    capnorm_kernel<<<C_N * W_N, 64, 0, stream>>>(captions, capn);
    attn_gemm_kernel<<<dim3(M_N / BM, N_N / BN), 256, 0, stream>>>(imgbf, capbf, attn);
    score_kernel<<<dim3(I_N, C_N / CG), 192, 0, stream>>>(attn, Gw, capn, cap_lens, scores);
    final_kernel<<<1, 128, 0, stream>>>(scores, out);
}